// Round 2
// baseline (586.643 us; speedup 1.0000x reference)
//
#include <hip/hip_runtime.h>

// Problem constants
#define BQ 2048
#define NS 32768
#define DIM 256
#define BM 128        // queries per block
#define BN 128        // supports per inner tile
#define BK 16         // k staged per step
#define NTILES 4      // support tiles per block (loop)
#define GY (NS / (BN * NTILES))   // 64 partial chunks per query
#define LDT (BM + 4)  // 132: keeps 16B row alignment, staging stores 2-way max

// ---------------------------------------------------------------------------
// Kernel 1: s2[n] = ||support[n]||^2. One wave per row.
// ---------------------------------------------------------------------------
__global__ __launch_bounds__(256) void s2_kernel(const float* __restrict__ s,
                                                 float* __restrict__ s2) {
    int wave = threadIdx.x >> 6;
    int lane = threadIdx.x & 63;
    int row  = blockIdx.x * 4 + wave;
    const float4* p = (const float4*)(s + (size_t)row * DIM);
    float4 v = p[lane];
    float sum = v.x * v.x + v.y * v.y + v.z * v.z + v.w * v.w;
#pragma unroll
    for (int off = 32; off > 0; off >>= 1)
        sum += __shfl_xor(sum, off);
    if (lane == 0) s2[row] = sum;
}

// ---------------------------------------------------------------------------
// Kernel 2: 128x128 block tile, 8x8 register micro-tile per thread.
// Score = s2[n] - 2*dot(x,s) (monotone in reference distance).
// LDS: Xs/Bs [BK][132] k-major, both streamed; 16.9 KB total.
// Micro-tile columns split (tx*4, 64+tx*4) -> ds_read_b128 at <=2-way aliasing.
// ---------------------------------------------------------------------------
__global__ __launch_bounds__(256, 4) void knn_main(const float* __restrict__ x,
                                                   const float* __restrict__ sup,
                                                   const float* __restrict__ s2g,
                                                   float* __restrict__ pvals,
                                                   int* __restrict__ pidx) {
    __shared__ float Xs[BK][LDT];
    __shared__ float Bs[BK][LDT];

    const int tid = threadIdx.x;
    const int tx  = tid & 15;
    const int ty  = tid >> 4;
    const int m0  = blockIdx.x * BM;
    const int by  = blockIdx.y;

    // staging role: thread -> row (tid/4) and (64 + tid/4), k-quad (tid%4)*4
    const int srow = tid >> 2;
    const int skq  = (tid & 3) * 4;

    float rmin[8];
    int   ridx[8];
#pragma unroll
    for (int i = 0; i < 8; ++i) { rmin[i] = 3.4e38f; ridx[i] = 0x7fffffff; }

    const float* xr0 = x + (size_t)(m0 + srow) * DIM + skq;
    const float* xr1 = x + (size_t)(m0 + 64 + srow) * DIM + skq;

    for (int nt = 0; nt < NTILES; ++nt) {
        const int n0 = (by * NTILES + nt) * BN;
        const float* sr0 = sup + (size_t)(n0 + srow) * DIM + skq;
        const float* sr1 = sup + (size_t)(n0 + 64 + srow) * DIM + skq;

        float acc[8][8];
#pragma unroll
        for (int i = 0; i < 8; ++i)
#pragma unroll
            for (int j = 0; j < 8; ++j) acc[i][j] = 0.0f;

        for (int kt = 0; kt < DIM / BK; ++kt) {
            const int k0 = kt * BK;
            // issue global loads to registers before the barrier
            float4 xv0 = *(const float4*)(xr0 + k0);
            float4 xv1 = *(const float4*)(xr1 + k0);
            float4 sv0 = *(const float4*)(sr0 + k0);
            float4 sv1 = *(const float4*)(sr1 + k0);
            __syncthreads();   // previous iteration's LDS reads complete
            Xs[skq + 0][srow] = xv0.x; Xs[skq + 1][srow] = xv0.y;
            Xs[skq + 2][srow] = xv0.z; Xs[skq + 3][srow] = xv0.w;
            Xs[skq + 0][64 + srow] = xv1.x; Xs[skq + 1][64 + srow] = xv1.y;
            Xs[skq + 2][64 + srow] = xv1.z; Xs[skq + 3][64 + srow] = xv1.w;
            Bs[skq + 0][srow] = sv0.x; Bs[skq + 1][srow] = sv0.y;
            Bs[skq + 2][srow] = sv0.z; Bs[skq + 3][srow] = sv0.w;
            Bs[skq + 0][64 + srow] = sv1.x; Bs[skq + 1][64 + srow] = sv1.y;
            Bs[skq + 2][64 + srow] = sv1.z; Bs[skq + 3][64 + srow] = sv1.w;
            __syncthreads();

#pragma unroll
            for (int k = 0; k < BK; ++k) {
                float4 a0 = *(const float4*)&Xs[k][ty * 4];
                float4 a1 = *(const float4*)&Xs[k][64 + ty * 4];
                float4 b0 = *(const float4*)&Bs[k][tx * 4];
                float4 b1 = *(const float4*)&Bs[k][64 + tx * 4];
                float a[8] = {a0.x, a0.y, a0.z, a0.w, a1.x, a1.y, a1.z, a1.w};
                float b[8] = {b0.x, b0.y, b0.z, b0.w, b1.x, b1.y, b1.z, b1.w};
#pragma unroll
                for (int i = 0; i < 8; ++i)
#pragma unroll
                    for (int j = 0; j < 8; ++j)
                        acc[i][j] = fmaf(a[i], b[j], acc[i][j]);
            }
        }

        // ---- fused argmin epilogue for this 128-support tile ----
        const int nb0 = n0 + tx * 4;
        const int nb1 = n0 + 64 + tx * 4;
        float4 s20 = *(const float4*)(s2g + nb0);
        float4 s21 = *(const float4*)(s2g + nb1);
        float s2a[8] = {s20.x, s20.y, s20.z, s20.w, s21.x, s21.y, s21.z, s21.w};
        int   nca[8] = {nb0, nb0 + 1, nb0 + 2, nb0 + 3,
                        nb1, nb1 + 1, nb1 + 2, nb1 + 3};
#pragma unroll
        for (int i = 0; i < 8; ++i)
#pragma unroll
            for (int j = 0; j < 8; ++j) {
                float sc = fmaf(-2.0f, acc[i][j], s2a[j]);
                if (sc < rmin[i] || (sc == rmin[i] && nca[j] < ridx[i])) {
                    rmin[i] = sc; ridx[i] = nca[j];
                }
            }
    }

    // ---- cross-thread reduce: 16 tx-lanes per query row ----
    __syncthreads();                      // done with Xs/Bs as tiles
    float* redv = (float*)Xs;             // [128][16] floats = 8 KB
    int*   redi = (int*)Bs;               // [128][16] ints  = 8 KB
#pragma unroll
    for (int i = 0; i < 8; ++i) {
        int mrow = (i < 4) ? (ty * 4 + i) : (64 + ty * 4 + (i - 4));
        redv[mrow * 16 + tx] = rmin[i];
        redi[mrow * 16 + tx] = ridx[i];
    }
    __syncthreads();
    if (tid < BM) {
        float best = redv[tid * 16];
        int   bi   = redi[tid * 16];
#pragma unroll
        for (int t = 1; t < 16; ++t) {
            float v  = redv[tid * 16 + t];
            int   ix = redi[tid * 16 + t];
            if (v < best || (v == best && ix < bi)) { best = v; bi = ix; }
        }
        pvals[(size_t)(m0 + tid) * GY + by] = best;
        pidx [(size_t)(m0 + tid) * GY + by] = bi;
    }
}

// ---------------------------------------------------------------------------
// Kernel 3: reduce GY=64 partials per query (one wave), label gather, one-hot.
// Runtime int64-vs-int32 label layout detection (labels in [0,100)).
// ---------------------------------------------------------------------------
__global__ __launch_bounds__(64) void finalize_kernel(const float* __restrict__ pvals,
                                                      const int* __restrict__ pidx,
                                                      const int* __restrict__ labels,
                                                      const int* __restrict__ ncp,
                                                      int* __restrict__ out) {
    const int b    = blockIdx.x;
    const int lane = threadIdx.x;
    float v  = pvals[(size_t)b * GY + lane];
    int   ix = pidx [(size_t)b * GY + lane];
#pragma unroll
    for (int off = 32; off > 0; off >>= 1) {
        float ov = __shfl_xor(v, off);
        int   oi = __shfl_xor(ix, off);
        if (ov < v || (ov == v && oi < ix)) { v = ov; ix = oi; }
    }
    // ix now uniform across the wave
    bool is64 = true;
    for (int i = 1; i < 128; i += 2)
        if (labels[i] != 0) { is64 = false; break; }
    const int lbl = is64 ? labels[2 * ix] : labels[ix];
    const int nc  = ncp[0];
    for (int c = lane; c < nc; c += 64)
        out[b * nc + c] = (c == lbl) ? 1 : 0;
}

// ---------------------------------------------------------------------------
extern "C" void kernel_launch(void* const* d_in, const int* in_sizes, int n_in,
                              void* d_out, int out_size, void* d_ws, size_t ws_size,
                              hipStream_t stream) {
    const float* x      = (const float*)d_in[0];
    const float* sup    = (const float*)d_in[1];
    const int*   labels = (const int*)d_in[2];
    const int*   ncp    = (const int*)d_in[3];
    int* out = (int*)d_out;

    float* s2    = (float*)d_ws;                 // 32768 floats
    float* pvals = s2 + NS;                      // 2048*64 floats
    int*   pidx  = (int*)(pvals + BQ * GY);      // 2048*64 ints

    s2_kernel<<<NS / 4, 256, 0, stream>>>(sup, s2);

    dim3 grid(BQ / BM, GY);
    knn_main<<<grid, 256, 0, stream>>>(x, sup, s2, pvals, pidx);

    finalize_kernel<<<BQ, 64, 0, stream>>>(pvals, pidx, labels, ncp, out);
}

// Round 3
// 490.893 us; speedup vs baseline: 1.1951x; 1.1951x over previous
//
#include <hip/hip_runtime.h>

// Problem constants
#define BQ 2048
#define NS 32768
#define DIM 256
#define BM 128        // queries per block
#define BN 128        // supports per inner tile
#define BK 16         // k staged per step
#define NTILES 4      // support tiles per block (loop)
#define GY (NS / (BN * NTILES))   // 64 partial chunks per query
#define LDT (BM + 4)  // 132: keeps 16B row alignment, staging stores 2-way max

// ---------------------------------------------------------------------------
// Kernel 1: s2[n] = ||support[n]||^2. One wave per row.
// ---------------------------------------------------------------------------
__global__ __launch_bounds__(256) void s2_kernel(const float* __restrict__ s,
                                                 float* __restrict__ s2) {
    int wave = threadIdx.x >> 6;
    int lane = threadIdx.x & 63;
    int row  = blockIdx.x * 4 + wave;
    const float4* p = (const float4*)(s + (size_t)row * DIM);
    float4 v = p[lane];
    float sum = v.x * v.x + v.y * v.y + v.z * v.z + v.w * v.w;
#pragma unroll
    for (int off = 32; off > 0; off >>= 1)
        sum += __shfl_xor(sum, off);
    if (lane == 0) s2[row] = sum;
}

// ---------------------------------------------------------------------------
// Kernel 2: 128x128 block tile, 8x8 register micro-tile per thread.
// Score = s2[n] - 2*dot(x,s) (monotone in reference distance).
// NOTE: no minwaves arg in __launch_bounds__ — (256,4) capped VGPRs at 64 on
// gfx950 and spilled the 64-float accumulator to scratch (562 MB WRITE_SIZE,
// R2). Plain (256) compiles spill-free.
// ---------------------------------------------------------------------------
__global__ __launch_bounds__(256) void knn_main(const float* __restrict__ x,
                                                const float* __restrict__ sup,
                                                const float* __restrict__ s2g,
                                                float* __restrict__ pvals,
                                                int* __restrict__ pidx) {
    __shared__ float Xs[BK][LDT];
    __shared__ float Bs[BK][LDT];

    const int tid = threadIdx.x;
    const int tx  = tid & 15;
    const int ty  = tid >> 4;
    const int m0  = blockIdx.x * BM;
    const int by  = blockIdx.y;

    // staging role: thread -> rows (tid/4) and (64 + tid/4), k-quad (tid%4)*4
    const int srow = tid >> 2;
    const int skq  = (tid & 3) * 4;

    float rmin[8];
    int   ridx[8];
#pragma unroll
    for (int i = 0; i < 8; ++i) { rmin[i] = 3.4e38f; ridx[i] = 0x7fffffff; }

    const float* xr0 = x + (size_t)(m0 + srow) * DIM + skq;
    const float* xr1 = x + (size_t)(m0 + 64 + srow) * DIM + skq;

    for (int nt = 0; nt < NTILES; ++nt) {
        const int n0 = (by * NTILES + nt) * BN;
        const float* sr0 = sup + (size_t)(n0 + srow) * DIM + skq;
        const float* sr1 = sup + (size_t)(n0 + 64 + srow) * DIM + skq;

        float acc[8][8];
#pragma unroll
        for (int i = 0; i < 8; ++i)
#pragma unroll
            for (int j = 0; j < 8; ++j) acc[i][j] = 0.0f;

        for (int kt = 0; kt < DIM / BK; ++kt) {
            const int k0 = kt * BK;
            // issue global loads to registers before the barrier
            float4 xv0 = *(const float4*)(xr0 + k0);
            float4 xv1 = *(const float4*)(xr1 + k0);
            float4 sv0 = *(const float4*)(sr0 + k0);
            float4 sv1 = *(const float4*)(sr1 + k0);
            __syncthreads();   // previous iteration's LDS reads complete
            Xs[skq + 0][srow] = xv0.x; Xs[skq + 1][srow] = xv0.y;
            Xs[skq + 2][srow] = xv0.z; Xs[skq + 3][srow] = xv0.w;
            Xs[skq + 0][64 + srow] = xv1.x; Xs[skq + 1][64 + srow] = xv1.y;
            Xs[skq + 2][64 + srow] = xv1.z; Xs[skq + 3][64 + srow] = xv1.w;
            Bs[skq + 0][srow] = sv0.x; Bs[skq + 1][srow] = sv0.y;
            Bs[skq + 2][srow] = sv0.z; Bs[skq + 3][srow] = sv0.w;
            Bs[skq + 0][64 + srow] = sv1.x; Bs[skq + 1][64 + srow] = sv1.y;
            Bs[skq + 2][64 + srow] = sv1.z; Bs[skq + 3][64 + srow] = sv1.w;
            __syncthreads();

#pragma unroll
            for (int k = 0; k < BK; ++k) {
                float4 a0 = *(const float4*)&Xs[k][ty * 4];
                float4 a1 = *(const float4*)&Xs[k][64 + ty * 4];
                float4 b0 = *(const float4*)&Bs[k][tx * 4];
                float4 b1 = *(const float4*)&Bs[k][64 + tx * 4];
                float a[8] = {a0.x, a0.y, a0.z, a0.w, a1.x, a1.y, a1.z, a1.w};
                float b[8] = {b0.x, b0.y, b0.z, b0.w, b1.x, b1.y, b1.z, b1.w};
#pragma unroll
                for (int i = 0; i < 8; ++i)
#pragma unroll
                    for (int j = 0; j < 8; ++j)
                        acc[i][j] = fmaf(a[i], b[j], acc[i][j]);
            }
        }

        // ---- fused argmin epilogue for this 128-support tile ----
        const int nb0 = n0 + tx * 4;
        const int nb1 = n0 + 64 + tx * 4;
        float4 s20 = *(const float4*)(s2g + nb0);
        float4 s21 = *(const float4*)(s2g + nb1);
        float s2a[8] = {s20.x, s20.y, s20.z, s20.w, s21.x, s21.y, s21.z, s21.w};
        int   nca[8] = {nb0, nb0 + 1, nb0 + 2, nb0 + 3,
                        nb1, nb1 + 1, nb1 + 2, nb1 + 3};
#pragma unroll
        for (int i = 0; i < 8; ++i)
#pragma unroll
            for (int j = 0; j < 8; ++j) {
                float sc = fmaf(-2.0f, acc[i][j], s2a[j]);
                if (sc < rmin[i] || (sc == rmin[i] && nca[j] < ridx[i])) {
                    rmin[i] = sc; ridx[i] = nca[j];
                }
            }
    }

    // ---- cross-thread reduce: 16 tx-lanes per query row ----
    __syncthreads();                      // done with Xs/Bs as tiles
    float* redv = (float*)Xs;             // [128][16] floats = 8 KB
    int*   redi = (int*)Bs;               // [128][16] ints  = 8 KB
#pragma unroll
    for (int i = 0; i < 8; ++i) {
        int mrow = (i < 4) ? (ty * 4 + i) : (64 + ty * 4 + (i - 4));
        redv[mrow * 16 + tx] = rmin[i];
        redi[mrow * 16 + tx] = ridx[i];
    }
    __syncthreads();
    if (tid < BM) {
        float best = redv[tid * 16];
        int   bi   = redi[tid * 16];
#pragma unroll
        for (int t = 1; t < 16; ++t) {
            float v  = redv[tid * 16 + t];
            int   ix = redi[tid * 16 + t];
            if (v < best || (v == best && ix < bi)) { best = v; bi = ix; }
        }
        pvals[(size_t)(m0 + tid) * GY + by] = best;
        pidx [(size_t)(m0 + tid) * GY + by] = bi;
    }
}

// ---------------------------------------------------------------------------
// Kernel 3: reduce GY=64 partials per query (one wave), label gather, one-hot.
// Runtime int64-vs-int32 label layout detection (labels in [0,100)).
// ---------------------------------------------------------------------------
__global__ __launch_bounds__(64) void finalize_kernel(const float* __restrict__ pvals,
                                                      const int* __restrict__ pidx,
                                                      const int* __restrict__ labels,
                                                      const int* __restrict__ ncp,
                                                      int* __restrict__ out) {
    const int b    = blockIdx.x;
    const int lane = threadIdx.x;
    float v  = pvals[(size_t)b * GY + lane];
    int   ix = pidx [(size_t)b * GY + lane];
#pragma unroll
    for (int off = 32; off > 0; off >>= 1) {
        float ov = __shfl_xor(v, off);
        int   oi = __shfl_xor(ix, off);
        if (ov < v || (ov == v && oi < ix)) { v = ov; ix = oi; }
    }
    // ix now uniform across the wave
    bool is64 = true;
    for (int i = 1; i < 128; i += 2)
        if (labels[i] != 0) { is64 = false; break; }
    const int lbl = is64 ? labels[2 * ix] : labels[ix];
    const int nc  = ncp[0];
    for (int c = lane; c < nc; c += 64)
        out[b * nc + c] = (c == lbl) ? 1 : 0;
}

// ---------------------------------------------------------------------------
extern "C" void kernel_launch(void* const* d_in, const int* in_sizes, int n_in,
                              void* d_out, int out_size, void* d_ws, size_t ws_size,
                              hipStream_t stream) {
    const float* x      = (const float*)d_in[0];
    const float* sup    = (const float*)d_in[1];
    const int*   labels = (const int*)d_in[2];
    const int*   ncp    = (const int*)d_in[3];
    int* out = (int*)d_out;

    float* s2    = (float*)d_ws;                 // 32768 floats
    float* pvals = s2 + NS;                      // 2048*64 floats
    int*   pidx  = (int*)(pvals + BQ * GY);      // 2048*64 ints

    s2_kernel<<<NS / 4, 256, 0, stream>>>(sup, s2);

    dim3 grid(BQ / BM, GY);
    knn_main<<<grid, 256, 0, stream>>>(x, sup, s2, pvals, pidx);

    finalize_kernel<<<BQ, 64, 0, stream>>>(pvals, pidx, labels, ncp, out);
}